// Round 17
// baseline (99.491 us; speedup 1.0000x reference)
//
#include <hip/hip_runtime.h>
#include <stdint.h>

typedef unsigned long long u64;

#define NMS_T 0.7f
#define MINSZ 16.0f
#define NPRE 6000
#define NPOST 300
#define CA   384
#define NG   6          // groups of 64 = CA/64
#define CAPA 2048
#define CAP6 8192
#define NBIN 2048
#define NSLOT 32
#define GRIDC 128

// ---- workspace layout (bytes) ----
#define OFF_CAND6  0                          // CAP6*8 (fallback only)
#define OFF_CANDA  (OFF_CAND6 + CAP6*8)       // CAPA*8
#define OFF_ORDER6 (OFF_CANDA + CAPA*8)       // NPRE*4  (fallback)
#define OFF_ROI6   (OFF_ORDER6 + NPRE*4)      // NPRE*16 (fallback)
#define OFF_SLOT   (OFF_ROI6 + NPRE*16)       // NSLOT*NBIN*4
#define OFF_CNT    (OFF_SLOT + NSLOT*NBIN*4)  // 32: [2]=done [3]=galloc

__device__ __forceinline__ unsigned inv_key(float s) {
    unsigned u = __float_as_uint(s);
    unsigned k = (u & 0x80000000u) ? ~u : (u | 0x80000000u);
    return ~k;   // ascending inv == descending score
}

__device__ __forceinline__ float4 decode_box(const float4 a, const float4 l,
                                             float ih, float iw) {
    float h  = a.z - a.x;
    float w  = a.w - a.y;
    float cy = a.x + 0.5f * h;
    float cx = a.y + 0.5f * w;
    float ncy = l.x * h + cy;
    float ncx = l.y * w + cx;
    float nh  = expf(l.z) * h;
    float nw  = expf(l.w) * w;
    float y1 = fminf(fmaxf(ncy - 0.5f * nh, 0.0f), ih);
    float x1 = fminf(fmaxf(ncx - 0.5f * nw, 0.0f), iw);
    float y2 = fminf(fmaxf(ncy + 0.5f * nh, 0.0f), ih);
    float x2 = fminf(fmaxf(ncx + 0.5f * nw, 0.0f), iw);
    return make_float4(y1, x1, y2, x2);
}

__device__ __forceinline__ int sbin_of(float s) {
    int b = (int)(s * 2048.0f);
    b = b < 0 ? 0 : (b > 2047 ? 2047 : b);
    return 2047 - b;           // ascending = descending score
}

// fast block scan of 2048-bin histogram (2 barriers): bins containing ranks t0/t1
__device__ void fastscan2048(const unsigned* __restrict__ h, unsigned t0, unsigned t1,
                             unsigned* swave, unsigned* res) {
    int t = threadIdx.x;
    unsigned vals[8], s = 0;
#pragma unroll
    for (int j = 0; j < 8; ++j) { vals[j] = h[t * 8 + j]; s += vals[j]; }
    unsigned inc = s;
#pragma unroll
    for (int off = 1; off < 64; off <<= 1) {
        unsigned o = (unsigned)__shfl_up((int)inc, off, 64);
        if ((t & 63) >= off) inc += o;
    }
    if ((t & 63) == 63) swave[t >> 6] = inc;
    __syncthreads();
    unsigned wbase = 0;
    for (int w = 0; w < (t >> 6); ++w) wbase += swave[w];
    unsigned run = wbase + inc - s;
#pragma unroll
    for (int j = 0; j < 8; ++j) {
        unsigned c = vals[j];
        if (run < t0 && run + c >= t0) { res[0] = t * 8 + j; res[1] = run; }
        if (t1 && run < t1 && run + c >= t1) { res[2] = t * 8 + j; res[3] = run; }
        run += c;
    }
    __syncthreads();
}

// ---- 1: score-only histogram; 8x float4 register-batched loads ----
__global__ void __launch_bounds__(256) k_hist(const float* __restrict__ score, int n,
                                              unsigned* __restrict__ slots,
                                              unsigned* __restrict__ cnts) {
    __shared__ unsigned lh[NBIN];
    for (int b = threadIdx.x; b < NBIN; b += 256) lh[b] = 0;
    if (blockIdx.x == 0 && threadIdx.x < 8) cnts[threadIdx.x] = 0;
    __syncthreads();
    int gtid = blockIdx.x * 256 + threadIdx.x;
    int T = gridDim.x * 256;
    int n4 = n >> 2;
    const float4* s4 = (const float4*)score;
    for (int idx0 = gtid; idx0 < n4; idx0 += T * 8) {
        float4 v[8]; int ok[8];
#pragma unroll
        for (int k = 0; k < 8; ++k) {
            int idx = idx0 + k * T;
            ok[k] = idx < n4;
            v[k] = ok[k] ? s4[idx] : make_float4(0.f, 0.f, 0.f, 0.f);
        }
#pragma unroll
        for (int k = 0; k < 8; ++k) if (ok[k]) {
            atomicAdd(&lh[sbin_of(v[k].x)], 1u);
            atomicAdd(&lh[sbin_of(v[k].y)], 1u);
            atomicAdd(&lh[sbin_of(v[k].z)], 1u);
            atomicAdd(&lh[sbin_of(v[k].w)], 1u);
        }
    }
    for (int i = (n4 << 2) + gtid; i < n; i += T) atomicAdd(&lh[sbin_of(score[i])], 1u);
    __syncthreads();
    for (int b = threadIdx.x; b < NBIN; b += 256)
        slots[blockIdx.x * NBIN + b] = lh[b];
}

struct SmC2 {
    u64 skey[CAPA];          // 16 KB
    unsigned shist[NBIN];    // 8 KB
    unsigned sprefix[NBIN];  // 8 KB
    u64 matT[NG * CA];       // 18.4 KB  transposed: matT[gr*CA+col]
};
struct SmFb {
    u64   lk[CAP6];          // 64 KB
    float y1[NPOST], x1[NPOST], y2[NPOST], x2[NPOST], ar[NPOST];
};
union SmU2 {
    unsigned hsum[NBIN];     // threshold stage
    u64 win[CAPA];           // winner collection
    SmC2 c;                  // final-block rank/matrix
    SmFb fb;                 // fallback
};

// ---- 2: single pass collect -> last block does rank/matrix/scan/output ----
__global__ void __launch_bounds__(256) k_main(
        const float4* __restrict__ loc, const float* __restrict__ score,
        const float4* __restrict__ anchor, const int* __restrict__ ph,
        const int* __restrict__ pw, int n, const unsigned* __restrict__ slots,
        u64* __restrict__ candA, u64* __restrict__ cand6, unsigned* __restrict__ cnts,
        unsigned* __restrict__ order6, float4* __restrict__ roi6,
        float* __restrict__ out) {
    __shared__ SmU2 sm;
    __shared__ unsigned swave[8], res[8];
    __shared__ unsigned sNW, sBase, sInvLo;
    __shared__ int sIsLast, snk, sflag;
    __shared__ float4 sroi[CA];
    __shared__ float  sarea[CA];
    __shared__ unsigned svalid[CA / 32];
    __shared__ u64 skm[NG];

    const int tid = threadIdx.x, bid = blockIdx.x;
    const int gtid = bid * 256 + tid;
    const int T = GRIDC * 256;
    const float ih = (float)ph[0], iw = (float)pw[0];
    const int n4 = n >> 2, ntail = n4 << 2;
    const float4* s4 = (const float4*)score;

    // ---- thresholds from slot histogram (every block; deterministic) ----
    for (int b = tid; b < NBIN; b += 256) {
        unsigned s = 0;
#pragma unroll 4
        for (int sl = 0; sl < NSLOT; ++sl) s += slots[sl * NBIN + b];
        sm.hsum[b] = s;
    }
    __syncthreads();
    fastscan2048(sm.hsum, CA, NPRE, swave, res);
    const unsigned bA = res[0], b6 = res[2];
    const unsigned cntA_total = res[1] + sm.hsum[bA];
    const unsigned cnt6_total = res[3] + sm.hsum[b6];
    const bool mainValid = (cntA_total <= CAPA);
    if (tid == 0) sNW = 0;
    __syncthreads();                    // hsum dead after this point (union reuse)

    // ---- single pass: collect winners (hb <= bA) into LDS ----
    if (mainValid) {
        for (int idx0 = gtid; idx0 < n4; idx0 += T * 8) {
            float4 v[8]; int ok[8];
#pragma unroll
            for (int k = 0; k < 8; ++k) {
                int idx = idx0 + k * T;
                ok[k] = idx < n4;
                v[k] = ok[k] ? s4[idx] : make_float4(0.f, 0.f, 0.f, 0.f);
            }
#pragma unroll
            for (int k = 0; k < 8; ++k) if (ok[k]) {
                float sc[4] = {v[k].x, v[k].y, v[k].z, v[k].w};
                int ib = (idx0 + k * T) << 2;
#pragma unroll
                for (int c = 0; c < 4; ++c) {
                    if ((unsigned)sbin_of(sc[c]) <= bA) {
                        int i = ib + c;
                        float4 r = decode_box(anchor[i], loc[i], ih, iw);
                        bool valid = ((r.z - r.x) >= MINSZ) && ((r.w - r.y) >= MINSZ);
                        float ms = valid ? sc[c] : -__builtin_inff();
                        u64 key = ((u64)inv_key(ms) << 32) | (unsigned)i;
                        unsigned p = atomicAdd(&sNW, 1u);
                        if (p < CAPA) sm.win[p] = key;
                    }
                }
            }
        }
        for (int i = ntail + gtid; i < n; i += T) {
            float s = score[i];
            if ((unsigned)sbin_of(s) <= bA) {
                float4 r = decode_box(anchor[i], loc[i], ih, iw);
                bool valid = ((r.z - r.x) >= MINSZ) && ((r.w - r.y) >= MINSZ);
                float ms = valid ? s : -__builtin_inff();
                u64 key = ((u64)inv_key(ms) << 32) | (unsigned)i;
                unsigned p = atomicAdd(&sNW, 1u);
                if (p < CAPA) sm.win[p] = key;
            }
        }
    }
    __syncthreads();
    unsigned NW = sNW;
    if (tid == 0 && NW) sBase = atomicAdd(&cnts[3], NW);
    __syncthreads();
    if (mainValid && NW) {
        unsigned base = sBase;
        for (unsigned i = tid; i < NW; i += 256) candA[base + i] = sm.win[i];
    }
    // arrive-only done counter; LAST block continues alone (no waiting)
    __threadfence();
    __syncthreads();
    if (tid == 0) {
        unsigned d = atomicAdd(&cnts[2], 1u);
        sIsLast = (d == GRIDC - 1);
    }
    __syncthreads();
    if (!sIsLast) return;
    __threadfence();   // acquire: all blocks' candA writes visible

    // ================= final tail (one block) =================
    unsigned MA = mainValid ? cntA_total : 0;
    if (mainValid) {
        if (tid == 0) sInvLo = 0xFFFFFFFFu;
        for (int b = tid; b < NBIN; b += 256) sm.c.shist[b] = 0;
        for (int r = tid; r < CA; r += 256) { sroi[r] = make_float4(0.f,0.f,0.f,0.f); sarea[r] = 0.f; }
        if (tid < CA / 32) svalid[tid] = 0;
        u64 kreg[8];
#pragma unroll
        for (int k = 0; k < 8; ++k) {
            unsigned i = tid + k * 256u;
            kreg[k] = (i < MA) ? candA[i] : ~0ULL;
        }
        unsigned mymin = 0xFFFFFFFFu;
#pragma unroll
        for (int k = 0; k < 8; ++k) {
            unsigned hi = (unsigned)(kreg[k] >> 32);
            mymin = mymin < hi ? mymin : hi;
        }
#pragma unroll
        for (int off = 32; off; off >>= 1) {
            unsigned o = (unsigned)__shfl_down((int)mymin, off, 64);
            mymin = mymin < o ? mymin : o;
        }
        if ((tid & 63) == 0) atomicMin(&sInvLo, mymin);
        __syncthreads();
        unsigned invLo = sInvLo;
#pragma unroll
        for (int k = 0; k < 8; ++k) {
            unsigned i = tid + k * 256u;
            if (i < MA) {
                unsigned d = ((unsigned)(kreg[k] >> 32) - invLo) >> 3;
                atomicAdd(&sm.c.shist[d > 2047u ? 2047u : d], 1u);
            }
        }
        __syncthreads();
        {   // fast exclusive prefix into sprefix
            unsigned vals[8], s = 0;
#pragma unroll
            for (int j = 0; j < 8; ++j) { vals[j] = sm.c.shist[tid * 8 + j]; s += vals[j]; }
            unsigned inc = s;
#pragma unroll
            for (int off = 1; off < 64; off <<= 1) {
                unsigned o = (unsigned)__shfl_up((int)inc, off, 64);
                if ((tid & 63) >= off) inc += o;
            }
            if ((tid & 63) == 63) swave[tid >> 6] = inc;
            __syncthreads();
            unsigned wbase = 0;
            for (int w = 0; w < (tid >> 6); ++w) wbase += swave[w];
            unsigned run = wbase + inc - s;
#pragma unroll
            for (int j = 0; j < 8; ++j) { sm.c.sprefix[tid * 8 + j] = run; run += vals[j]; }
        }
        __syncthreads();
#pragma unroll
        for (int k = 0; k < 8; ++k) {
            unsigned i = tid + k * 256u;
            if (i < MA) {
                unsigned d = ((unsigned)(kreg[k] >> 32) - invLo) >> 3;
                d = d > 2047u ? 2047u : d;
                unsigned pos = atomicAdd(&sm.c.sprefix[d], 1u);
                sm.c.skey[pos] = kreg[k];
            }
        }
        __syncthreads();
#pragma unroll
        for (int k = 0; k < 8; ++k) {
            unsigned p = tid + k * 256u;
            if (p < MA) {
                u64 key = sm.c.skey[p];
                unsigned d = ((unsigned)(key >> 32) - invLo) >> 3;
                d = d > 2047u ? 2047u : d;
                unsigned e = sm.c.sprefix[d];
                unsigned s0 = e - sm.c.shist[d];
                int rank = (int)s0;
                for (unsigned q = s0; q < e; ++q) rank += (sm.c.skey[q] < key) ? 1 : 0;
                if (rank < CA) {
                    unsigned idx = (unsigned)key;
                    float4 b = decode_box(anchor[idx], loc[idx], ih, iw);
                    sroi[rank] = b;
                    sarea[rank] = (b.z - b.x) * (b.w - b.y);
                    if (((b.z - b.x) >= MINSZ) && ((b.w - b.y) >= MINSZ))
                        atomicOr(&svalid[rank >> 5], 1u << (rank & 31));
                }
            }
        }
        __syncthreads();
        // transposed suppression matrix in LDS: matT[gr*CA+jcol] bit c = row 64*gr+c sup col jcol
        for (int task = tid; task < NG * CA; task += 256) {
            int gr = task / CA;
            int jcol = task - gr * CA;
            int j0 = gr << 6;
            u64 bits = 0;
            if (j0 < jcol) {
                float4 b = sroi[jcol];
                float ab = sarea[jcol];
                int cmax = jcol - j0; cmax = cmax > 64 ? 64 : cmax;
                for (int c = 0; c < cmax; ++c) {
                    int row = j0 + c;
                    float4 r = sroi[row];
                    float yy1 = fmaxf(r.x, b.x);
                    float xx1 = fmaxf(r.y, b.y);
                    float yy2 = fminf(r.z, b.z);
                    float xx2 = fminf(r.w, b.w);
                    float inter = fmaxf(yy2 - yy1, 0.0f) * fmaxf(xx2 - xx1, 0.0f);
                    float iou = inter / (sarea[row] + ab - inter);  // ref op order
                    if (iou > NMS_T) bits |= (1ULL << c);
                }
            }
            sm.c.matT[gr * CA + jcol] = bits;
        }
        __syncthreads();
    }

    // ---- ballot scan (LDS matrix) ----
    int Ceff = (int)(cntA_total < (unsigned)CA ? cntA_total : (unsigned)CA);
    if (tid < 64 && mainValid) {
        u64 supfut[NG], W[NG], kmask[NG];
#pragma unroll
        for (int w = 0; w < NG; ++w) {
            supfut[w] = ~(((u64)svalid[2 * w + 1] << 32) | (u64)svalid[2 * w]);
            kmask[w] = 0ull;
        }
        int nk = 0;
        bool done = false;
#pragma unroll
        for (int g = 0; g < NG; ++g) {
#pragma unroll
            for (int gq = 0; gq < NG; ++gq) W[gq] = sm.c.matT[g * CA + 64 * gq + tid];
            int base = 64 * g;
            if (!done && base < Ceff) {
                u64 bound = (Ceff - base >= 64) ? ~0ull : ((1ull << (Ceff - base)) - 1ull);
                u64 live = ~supfut[g] & bound;
                u64 km = 0;
                while (live) {
                    int b = (int)__builtin_ctzll(live);
                    km |= 1ull << b;
                    ++nk;
                    if (nk == NPOST) { done = true; break; }
                    bool s = (W[g] >> b) & 1ull;
                    u64 supm = __ballot(s);
                    live &= ~(supm | (1ull << b));
                }
                kmask[g] = km;
                if (!done && g < NG - 1) {
#pragma unroll
                    for (int gq = 0; gq < NG; ++gq) {
                        if (gq > g) {
                            bool any = (W[gq] & km) != 0ull;
                            supfut[gq] |= __ballot(any);
                        }
                    }
                }
            }
        }
        if (tid == 0) {
            snk = nk;
            sflag = (nk < NPOST && cnt6_total > (unsigned)Ceff) ? 1 : 0;
#pragma unroll
            for (int g = 0; g < NG; ++g) skm[g] = kmask[g];
        }
    }
    if (tid == 0 && !mainValid) {
        snk = 0; sflag = 1;
#pragma unroll
        for (int g = 0; g < NG; ++g) skm[g] = 0ull;
    }
    __syncthreads();
    int nk = snk, flag = sflag;
    float4* out4 = (float4*)out;
    if (!flag) {
        int basepc[NG];
        {
            int run = 0;
#pragma unroll
            for (int g = 0; g < NG; ++g) { basepc[g] = run; run += __popcll(skm[g]); }
        }
        int wv = tid >> 6, j = tid & 63;
#pragma unroll
        for (int gg = 0; gg < 2; ++gg) {
            int g = wv + 4 * gg;
            if (g < NG) {
                u64 km = skm[g];
                if ((km >> j) & 1ull) {
                    int rank = basepc[g] + __popcll(km & ((1ull << j) - 1ull));
                    if (rank < NPOST) out4[rank] = sroi[64 * g + j];
                }
            }
        }
        for (int k = nk + tid; k < NPOST; k += 256) out4[k] = make_float4(0.f,0.f,0.f,0.f);
        return;
    }
    // ---------- exact fallback (gated; never taken on sane data) ----------
    // regenerate cand6 (top >= NPRE candidates) from raw input, single block
    __syncthreads();
    if (tid == 0) sNW = 0;
    __syncthreads();
    for (int i = tid; i < n; i += 256) {
        float s = score[i];
        if ((unsigned)sbin_of(s) <= b6) {
            float4 r = decode_box(anchor[i], loc[i], ih, iw);
            bool valid = ((r.z - r.x) >= MINSZ) && ((r.w - r.y) >= MINSZ);
            float ms = valid ? s : -__builtin_inff();
            u64 key = ((u64)inv_key(ms) << 32) | (unsigned)i;
            unsigned p = atomicAdd(&sNW, 1u);
            if (p < CAP6) cand6[p] = key;
        }
    }
    __threadfence();
    __syncthreads();
    unsigned M = sNW < (unsigned)CAP6 ? sNW : (unsigned)CAP6;
    for (unsigned i = tid; i < CAP6; i += 256) sm.fb.lk[i] = (i < M) ? cand6[i] : ~0ULL;
    for (int r = tid; r < NPRE; r += 256) order6[r] = 0xFFFFFFFFu;
    __syncthreads();
    for (unsigned c = tid; c < M; c += 256) {
        u64 key = sm.fb.lk[c];
        int rank = 0;
        for (unsigned j = 0; j < M; ++j) rank += (sm.fb.lk[j] < key) ? 1 : 0;
        if (rank < NPRE) order6[rank] = (unsigned)key;
    }
    __syncthreads();
    for (int r = tid; r < NPRE; r += 256) {
        unsigned idx = order6[r];
        float4 b = make_float4(0.f, 0.f, 0.f, 0.f);
        if (idx < (unsigned)n) b = decode_box(anchor[idx], loc[idx], ih, iw);
        roi6[r] = b;
    }
    __syncthreads();
    if (tid < 64) {
        int lane = tid;
        int nk2 = 0;
        for (int i = 0; i < NPRE; i++) {
            float4 b = roi6[i];
            float hs = b.z - b.x, wd = b.w - b.y;
            if (!(hs >= MINSZ && wd >= MINSZ)) continue;
            float ab = hs * wd;
            bool sup = false;
            for (int base = 0; base < nk2 && !sup; base += 64) {
                int t = base + lane;
                bool s = false;
                if (t < nk2) {
                    float yy1 = fmaxf(b.x, sm.fb.y1[t]);
                    float xx1 = fmaxf(b.y, sm.fb.x1[t]);
                    float yy2 = fminf(b.z, sm.fb.y2[t]);
                    float xx2 = fminf(b.w, sm.fb.x2[t]);
                    float inter = fmaxf(yy2 - yy1, 0.0f) * fmaxf(xx2 - xx1, 0.0f);
                    float iou = inter / (sm.fb.ar[t] + ab - inter);
                    s = iou > NMS_T;
                }
                sup = (__ballot(s) != 0ULL);
            }
            if (!sup) {
                if (lane == 0) {
                    sm.fb.y1[nk2] = b.x; sm.fb.x1[nk2] = b.y;
                    sm.fb.y2[nk2] = b.z; sm.fb.x2[nk2] = b.w; sm.fb.ar[nk2] = ab;
                }
                nk2++;
                if (nk2 == NPOST) break;
            }
        }
        for (int k = lane; k < NPOST; k += 64) {
            float4 o = make_float4(0.f, 0.f, 0.f, 0.f);
            if (k < nk2) o = make_float4(sm.fb.y1[k], sm.fb.x1[k], sm.fb.y2[k], sm.fb.x2[k]);
            out4[k] = o;
        }
    }
}

extern "C" void kernel_launch(void* const* d_in, const int* in_sizes, int n_in,
                              void* d_out, int out_size, void* d_ws, size_t ws_size,
                              hipStream_t stream) {
    const float4* loc    = (const float4*)d_in[0];
    const float*  score  = (const float*)d_in[1];
    const float4* anchor = (const float4*)d_in[2];
    const int*    ph     = (const int*)d_in[3];
    const int*    pw     = (const int*)d_in[4];
    int n = in_sizes[1];

    char* ws = (char*)d_ws;
    u64*      cand6  = (u64*)(ws + OFF_CAND6);
    u64*      candA  = (u64*)(ws + OFF_CANDA);
    unsigned* order6 = (unsigned*)(ws + OFF_ORDER6);
    float4*   roi6   = (float4*)(ws + OFF_ROI6);
    unsigned* slots  = (unsigned*)(ws + OFF_SLOT);
    unsigned* cnts   = (unsigned*)(ws + OFF_CNT);
    float* out = (float*)d_out;

    k_hist <<<dim3(NSLOT), dim3(256), 0, stream>>>(score, n, slots, cnts);
    k_main <<<dim3(GRIDC), dim3(256), 0, stream>>>(loc, score, anchor, ph, pw, n, slots,
                                                   candA, cand6, cnts, order6, roi6, out);
}

// Round 18
// 65.553 us; speedup vs baseline: 1.5177x; 1.5177x over previous
//
#include <hip/hip_runtime.h>
#include <stdint.h>

typedef unsigned long long u64;

#define NMS_T 0.7f
#define MINSZ 16.0f
#define NPRE 6000
#define NPOST 300
#define CA   384
#define NG   6          // groups of 64 = CA/64
#define CAPA 2048
#define CAP6 8192
#define NBIN 2048
#define NSLOT 32
#define GRIDC 128
#define GRIDR 9         // NG*CA/256

// ---- workspace layout (bytes) ----
#define OFF_CAND6  0                          // CAP6*8 (fallback only)
#define OFF_CANDA  (OFF_CAND6 + CAP6*8)       // CAPA*8
#define OFF_ORDER6 (OFF_CANDA + CAPA*8)       // NPRE*4  (fallback)
#define OFF_ROI6   (OFF_ORDER6 + NPRE*4)      // NPRE*16 (fallback)
#define OFF_GMAT   (OFF_ROI6 + NPRE*16)       // NG*CA*8 transposed gmatT[gr*CA+col]
#define OFF_SLOT   (OFF_GMAT + NG*CA*8)       // NSLOT*NBIN*4
#define OFF_CNT    (OFF_SLOT + NSLOT*NBIN*4)  // 32: [0]=cntA [1]=cnt6 [2]=done [3]=galloc [4]=bA [5]=b6

__device__ __forceinline__ unsigned inv_key(float s) {
    unsigned u = __float_as_uint(s);
    unsigned k = (u & 0x80000000u) ? ~u : (u | 0x80000000u);
    return ~k;   // ascending inv == descending score
}

__device__ __forceinline__ float4 decode_box(const float4 a, const float4 l,
                                             float ih, float iw) {
    float h  = a.z - a.x;
    float w  = a.w - a.y;
    float cy = a.x + 0.5f * h;
    float cx = a.y + 0.5f * w;
    float ncy = l.x * h + cy;
    float ncx = l.y * w + cx;
    float nh  = expf(l.z) * h;
    float nw  = expf(l.w) * w;
    float y1 = fminf(fmaxf(ncy - 0.5f * nh, 0.0f), ih);
    float x1 = fminf(fmaxf(ncx - 0.5f * nw, 0.0f), iw);
    float y2 = fminf(fmaxf(ncy + 0.5f * nh, 0.0f), ih);
    float x2 = fminf(fmaxf(ncx + 0.5f * nw, 0.0f), iw);
    return make_float4(y1, x1, y2, x2);
}

__device__ __forceinline__ int sbin_of(float s) {
    int b = (int)(s * 2048.0f);
    b = b < 0 ? 0 : (b > 2047 ? 2047 : b);
    return 2047 - b;           // ascending = descending score
}

// fast block scan of 2048-bin histogram (2 barriers): bins containing ranks t0/t1
__device__ void fastscan2048(const unsigned* __restrict__ h, unsigned t0, unsigned t1,
                             unsigned* swave, unsigned* res) {
    int t = threadIdx.x;
    unsigned vals[8], s = 0;
#pragma unroll
    for (int j = 0; j < 8; ++j) { vals[j] = h[t * 8 + j]; s += vals[j]; }
    unsigned inc = s;
#pragma unroll
    for (int off = 1; off < 64; off <<= 1) {
        unsigned o = (unsigned)__shfl_up((int)inc, off, 64);
        if ((t & 63) >= off) inc += o;
    }
    if ((t & 63) == 63) swave[t >> 6] = inc;
    __syncthreads();
    unsigned wbase = 0;
    for (int w = 0; w < (t >> 6); ++w) wbase += swave[w];
    unsigned run = wbase + inc - s;
#pragma unroll
    for (int j = 0; j < 8; ++j) {
        unsigned c = vals[j];
        if (run < t0 && run + c >= t0) { res[0] = t * 8 + j; res[1] = run; }
        if (t1 && run < t1 && run + c >= t1) { res[2] = t * 8 + j; res[3] = run; }
        run += c;
    }
    __syncthreads();
}

// ---- 1: score-only histogram; 8x float4 register-batched loads ----
__global__ void __launch_bounds__(256) k_hist(const float* __restrict__ score, int n,
                                              unsigned* __restrict__ slots,
                                              unsigned* __restrict__ cnts) {
    __shared__ unsigned lh[NBIN];
    for (int b = threadIdx.x; b < NBIN; b += 256) lh[b] = 0;
    if (blockIdx.x == 0 && threadIdx.x < 8) cnts[threadIdx.x] = 0;
    __syncthreads();
    int gtid = blockIdx.x * 256 + threadIdx.x;
    int T = gridDim.x * 256;
    int n4 = n >> 2;
    const float4* s4 = (const float4*)score;
    for (int idx0 = gtid; idx0 < n4; idx0 += T * 8) {
        float4 v[8]; int ok[8];
#pragma unroll
        for (int k = 0; k < 8; ++k) {
            int idx = idx0 + k * T;
            ok[k] = idx < n4;
            v[k] = ok[k] ? s4[idx] : make_float4(0.f, 0.f, 0.f, 0.f);
        }
#pragma unroll
        for (int k = 0; k < 8; ++k) if (ok[k]) {
            atomicAdd(&lh[sbin_of(v[k].x)], 1u);
            atomicAdd(&lh[sbin_of(v[k].y)], 1u);
            atomicAdd(&lh[sbin_of(v[k].z)], 1u);
            atomicAdd(&lh[sbin_of(v[k].w)], 1u);
        }
    }
    for (int i = (n4 << 2) + gtid; i < n; i += T) atomicAdd(&lh[sbin_of(score[i])], 1u);
    __syncthreads();
    for (int b = threadIdx.x; b < NBIN; b += 256)
        slots[blockIdx.x * NBIN + b] = lh[b];
}

// ---- 2: single-pass collect of top-bin winners (LDS buffer, 1 atomic/block) ----
union SmColl { unsigned hsum[NBIN]; u64 win[CAPA]; };

__global__ void __launch_bounds__(256) k_collect(
        const float4* __restrict__ loc, const float* __restrict__ score,
        const float4* __restrict__ anchor, const int* __restrict__ ph,
        const int* __restrict__ pw, int n, const unsigned* __restrict__ slots,
        u64* __restrict__ candA, unsigned* __restrict__ cnts) {
    __shared__ SmColl sm;
    __shared__ unsigned swave[8], res[8];
    __shared__ unsigned sNW, sBase;
    const int tid = threadIdx.x, bid = blockIdx.x;
    const int gtid = bid * 256 + tid;
    const int T = GRIDC * 256;
    const float ih = (float)ph[0], iw = (float)pw[0];
    const int n4 = n >> 2, ntail = n4 << 2;
    const float4* s4 = (const float4*)score;

    for (int b = tid; b < NBIN; b += 256) {
        unsigned s = 0;
#pragma unroll 4
        for (int sl = 0; sl < NSLOT; ++sl) s += slots[sl * NBIN + b];
        sm.hsum[b] = s;
    }
    __syncthreads();
    fastscan2048(sm.hsum, CA, NPRE, swave, res);
    const unsigned bA = res[0], b6 = res[2];
    const unsigned cntA_total = res[1] + sm.hsum[bA];
    const unsigned cnt6_total = res[3] + sm.hsum[b6];
    const bool mainValid = (cntA_total <= CAPA);
    if (bid == 0 && tid == 0) {
        cnts[0] = cntA_total; cnts[1] = cnt6_total; cnts[4] = bA; cnts[5] = b6;
    }
    if (tid == 0) sNW = 0;
    __syncthreads();                    // hsum dead (union reuse as win)

    if (mainValid) {
        for (int idx0 = gtid; idx0 < n4; idx0 += T * 8) {
            float4 v[8]; int ok[8];
#pragma unroll
            for (int k = 0; k < 8; ++k) {
                int idx = idx0 + k * T;
                ok[k] = idx < n4;
                v[k] = ok[k] ? s4[idx] : make_float4(0.f, 0.f, 0.f, 0.f);
            }
#pragma unroll
            for (int k = 0; k < 8; ++k) if (ok[k]) {
                float sc[4] = {v[k].x, v[k].y, v[k].z, v[k].w};
                int ib = (idx0 + k * T) << 2;
#pragma unroll
                for (int c = 0; c < 4; ++c) {
                    if ((unsigned)sbin_of(sc[c]) <= bA) {
                        int i = ib + c;
                        float4 r = decode_box(anchor[i], loc[i], ih, iw);
                        bool valid = ((r.z - r.x) >= MINSZ) && ((r.w - r.y) >= MINSZ);
                        float ms = valid ? sc[c] : -__builtin_inff();
                        u64 key = ((u64)inv_key(ms) << 32) | (unsigned)i;
                        unsigned p = atomicAdd(&sNW, 1u);
                        if (p < CAPA) sm.win[p] = key;   // p < CAPA guaranteed (NW<=cntA<=CAPA)
                    }
                }
            }
        }
        for (int i = ntail + gtid; i < n; i += T) {
            float s = score[i];
            if ((unsigned)sbin_of(s) <= bA) {
                float4 r = decode_box(anchor[i], loc[i], ih, iw);
                bool valid = ((r.z - r.x) >= MINSZ) && ((r.w - r.y) >= MINSZ);
                float ms = valid ? s : -__builtin_inff();
                u64 key = ((u64)inv_key(ms) << 32) | (unsigned)i;
                unsigned p = atomicAdd(&sNW, 1u);
                if (p < CAPA) sm.win[p] = key;
            }
        }
        __syncthreads();
        unsigned NW = sNW;
        if (tid == 0 && NW) sBase = atomicAdd(&cnts[3], NW);
        __syncthreads();
        if (NW) {
            unsigned base = sBase;
            for (unsigned i = tid; i < NW; i += 256) candA[base + i] = sm.win[i];
        }
    }
}

struct SmC {
    u64 skey[CAPA];          // 16 KB
    unsigned shist[NBIN];    // 8 KB
    unsigned sprefix[NBIN];  // 8 KB
};
struct SmFb {
    u64   lk[CAP6];          // 64 KB
    float y1[NPOST], x1[NPOST], y2[NPOST], x2[NPOST], ar[NPOST];
};
union SmR { SmC c; SmFb fb; };

// ---- 3: 9 blocks: counting-sort rank -> decode -> transposed matrix -> last-block scan ----
__global__ void __launch_bounds__(256) k_rankmat(
        const float4* __restrict__ loc, const float* __restrict__ score,
        const float4* __restrict__ anchor, const int* __restrict__ ph,
        const int* __restrict__ pw, int n,
        const u64* __restrict__ candA, u64* __restrict__ cand6,
        unsigned* __restrict__ cnts, u64* __restrict__ gmatT,
        unsigned* __restrict__ order6, float4* __restrict__ roi6,
        float* __restrict__ out) {
    __shared__ SmR sm;
    __shared__ float4 sroi[CA];
    __shared__ float  sarea[CA];
    __shared__ unsigned svalid[CA / 32];
    __shared__ unsigned swave[8];
    __shared__ unsigned sInvLo, sNW;
    __shared__ int sIsLast;
    __shared__ u64 skm[NG];
    __shared__ int snk, sflag;
    int tid = threadIdx.x;
    unsigned cntA = cnts[0], cnt6 = cnts[1];
    bool mainValid = (cntA <= CAPA);
    unsigned MA = mainValid ? cntA : 0;
    float ih = (float)ph[0], iw = (float)pw[0];

    if (mainValid) {
        if (tid == 0) sInvLo = 0xFFFFFFFFu;
        for (int b = tid; b < NBIN; b += 256) sm.c.shist[b] = 0;
        for (int r = tid; r < CA; r += 256) { sroi[r] = make_float4(0.f,0.f,0.f,0.f); sarea[r] = 0.f; }
        if (tid < CA / 32) svalid[tid] = 0;
        u64 kreg[8];
#pragma unroll
        for (int k = 0; k < 8; ++k) {
            unsigned i = tid + k * 256u;
            kreg[k] = (i < MA) ? candA[i] : ~0ULL;
        }
        unsigned mymin = 0xFFFFFFFFu;
#pragma unroll
        for (int k = 0; k < 8; ++k) {
            unsigned hi = (unsigned)(kreg[k] >> 32);
            mymin = mymin < hi ? mymin : hi;
        }
#pragma unroll
        for (int off = 32; off; off >>= 1) {
            unsigned o = (unsigned)__shfl_down((int)mymin, off, 64);
            mymin = mymin < o ? mymin : o;
        }
        if ((tid & 63) == 0) atomicMin(&sInvLo, mymin);
        __syncthreads();
        unsigned invLo = sInvLo;
#pragma unroll
        for (int k = 0; k < 8; ++k) {
            unsigned i = tid + k * 256u;
            if (i < MA) {
                unsigned d = ((unsigned)(kreg[k] >> 32) - invLo) >> 3;
                atomicAdd(&sm.c.shist[d > 2047u ? 2047u : d], 1u);
            }
        }
        __syncthreads();
        {   // fast exclusive prefix into sprefix
            unsigned vals[8], s = 0;
#pragma unroll
            for (int j = 0; j < 8; ++j) { vals[j] = sm.c.shist[tid * 8 + j]; s += vals[j]; }
            unsigned inc = s;
#pragma unroll
            for (int off = 1; off < 64; off <<= 1) {
                unsigned o = (unsigned)__shfl_up((int)inc, off, 64);
                if ((tid & 63) >= off) inc += o;
            }
            if ((tid & 63) == 63) swave[tid >> 6] = inc;
            __syncthreads();
            unsigned wbase = 0;
            for (int w = 0; w < (tid >> 6); ++w) wbase += swave[w];
            unsigned run = wbase + inc - s;
#pragma unroll
            for (int j = 0; j < 8; ++j) { sm.c.sprefix[tid * 8 + j] = run; run += vals[j]; }
        }
        __syncthreads();
#pragma unroll
        for (int k = 0; k < 8; ++k) {
            unsigned i = tid + k * 256u;
            if (i < MA) {
                unsigned d = ((unsigned)(kreg[k] >> 32) - invLo) >> 3;
                d = d > 2047u ? 2047u : d;
                unsigned pos = atomicAdd(&sm.c.sprefix[d], 1u);
                sm.c.skey[pos] = kreg[k];
            }
        }
        __syncthreads();
#pragma unroll
        for (int k = 0; k < 8; ++k) {
            unsigned p = tid + k * 256u;
            if (p < MA) {
                u64 key = sm.c.skey[p];
                unsigned d = ((unsigned)(key >> 32) - invLo) >> 3;
                d = d > 2047u ? 2047u : d;
                unsigned e = sm.c.sprefix[d];
                unsigned s0 = e - sm.c.shist[d];
                int rank = (int)s0;
                for (unsigned q = s0; q < e; ++q) rank += (sm.c.skey[q] < key) ? 1 : 0;
                if (rank < CA) {
                    unsigned idx = (unsigned)key;
                    float4 b = decode_box(anchor[idx], loc[idx], ih, iw);
                    sroi[rank] = b;
                    sarea[rank] = (b.z - b.x) * (b.w - b.y);
                    if (((b.z - b.x) >= MINSZ) && ((b.w - b.y) >= MINSZ))
                        atomicOr(&svalid[rank >> 5], 1u << (rank & 31));
                }
            }
        }
        __syncthreads();
        // transposed matrix slice: gmatT[gr*CA + jcol] bit c = row 64*gr+c suppresses col jcol
        {
            int task = blockIdx.x * 256 + tid;
            int gr = task / CA;
            int jcol = task - gr * CA;
            int j0 = gr << 6;
            u64 bits = 0;
            if (j0 < jcol) {
                float4 b = sroi[jcol];
                float ab = sarea[jcol];
                int cmax = jcol - j0; cmax = cmax > 64 ? 64 : cmax;
                for (int c = 0; c < cmax; ++c) {
                    int row = j0 + c;
                    float4 r = sroi[row];
                    float yy1 = fmaxf(r.x, b.x);
                    float xx1 = fmaxf(r.y, b.y);
                    float yy2 = fminf(r.z, b.z);
                    float xx2 = fminf(r.w, b.w);
                    float inter = fmaxf(yy2 - yy1, 0.0f) * fmaxf(xx2 - xx1, 0.0f);
                    float iou = inter / (sarea[row] + ab - inter);  // ref op order
                    if (iou > NMS_T) bits |= (1ULL << c);
                }
            }
            gmatT[gr * CA + jcol] = bits;
        }
    }
    // arrive-only done counter; last block continues alone
    __threadfence();
    __syncthreads();
    if (tid == 0) {
        unsigned d = atomicAdd(&cnts[2], 1u);
        sIsLast = (d == GRIDR - 1);
    }
    __syncthreads();
    if (!sIsLast) return;
    __threadfence();   // acquire

    // ---- ballot scan ----
    int Ceff = (int)(cntA < (unsigned)CA ? cntA : (unsigned)CA);
    if (tid < 64 && mainValid) {
        u64 supfut[NG], W[NG], nxtW[NG], kmask[NG];
#pragma unroll
        for (int w = 0; w < NG; ++w) {
            supfut[w] = ~(((u64)svalid[2 * w + 1] << 32) | (u64)svalid[2 * w]);
            kmask[w] = 0ull;
        }
#pragma unroll
        for (int gq = 0; gq < NG; ++gq) W[gq] = gmatT[0 * CA + 64 * gq + tid];
        int nk = 0;
        bool done = false;
#pragma unroll
        for (int g = 0; g < NG; ++g) {
            if (g < NG - 1) {
#pragma unroll
                for (int gq = 0; gq < NG; ++gq) nxtW[gq] = gmatT[(g + 1) * CA + 64 * gq + tid];
            }
            int base = 64 * g;
            if (!done && base < Ceff) {
                u64 bound = (Ceff - base >= 64) ? ~0ull : ((1ull << (Ceff - base)) - 1ull);
                u64 live = ~supfut[g] & bound;
                u64 km = 0;
                while (live) {
                    int b = (int)__builtin_ctzll(live);
                    km |= 1ull << b;
                    ++nk;
                    if (nk == NPOST) { done = true; break; }
                    bool s = (W[g] >> b) & 1ull;
                    u64 supm = __ballot(s);
                    live &= ~(supm | (1ull << b));
                }
                kmask[g] = km;
                if (!done && g < NG - 1) {
#pragma unroll
                    for (int gq = 0; gq < NG; ++gq) {
                        if (gq > g) {
                            bool any = (W[gq] & km) != 0ull;
                            supfut[gq] |= __ballot(any);
                        }
                    }
                }
            }
#pragma unroll
            for (int gq = 0; gq < NG; ++gq) W[gq] = nxtW[gq];
        }
        if (tid == 0) {
            snk = nk;
            sflag = (nk < NPOST && cnt6 > (unsigned)Ceff) ? 1 : 0;
#pragma unroll
            for (int g = 0; g < NG; ++g) skm[g] = kmask[g];
        }
    }
    if (tid == 0 && !mainValid) {
        snk = 0; sflag = 1;
#pragma unroll
        for (int g = 0; g < NG; ++g) skm[g] = 0ull;
    }
    __syncthreads();
    int nk = snk, flag = sflag;
    float4* out4 = (float4*)out;
    if (!flag) {
        int basepc[NG];
        {
            int run = 0;
#pragma unroll
            for (int g = 0; g < NG; ++g) { basepc[g] = run; run += __popcll(skm[g]); }
        }
        int wv = tid >> 6, j = tid & 63;
#pragma unroll
        for (int gg = 0; gg < 2; ++gg) {
            int g = wv + 4 * gg;
            if (g < NG) {
                u64 km = skm[g];
                if ((km >> j) & 1ull) {
                    int rank = basepc[g] + __popcll(km & ((1ull << j) - 1ull));
                    if (rank < NPOST) out4[rank] = sroi[64 * g + j];
                }
            }
        }
        for (int k = nk + tid; k < NPOST; k += 256) out4[k] = make_float4(0.f,0.f,0.f,0.f);
        return;
    }
    // ---------- exact fallback (gated; never taken on sane data) ----------
    __syncthreads();
    unsigned b6 = cnts[5];
    if (tid == 0) sNW = 0;
    __syncthreads();
    for (int i = tid; i < n; i += 256) {
        float s = score[i];
        if ((unsigned)sbin_of(s) <= b6) {
            float4 r = decode_box(anchor[i], loc[i], ih, iw);
            bool valid = ((r.z - r.x) >= MINSZ) && ((r.w - r.y) >= MINSZ);
            float ms = valid ? s : -__builtin_inff();
            u64 key = ((u64)inv_key(ms) << 32) | (unsigned)i;
            unsigned p = atomicAdd(&sNW, 1u);
            if (p < CAP6) cand6[p] = key;
        }
    }
    __threadfence();
    __syncthreads();
    unsigned M = sNW < (unsigned)CAP6 ? sNW : (unsigned)CAP6;
    for (unsigned i = tid; i < CAP6; i += 256) sm.fb.lk[i] = (i < M) ? cand6[i] : ~0ULL;
    for (int r = tid; r < NPRE; r += 256) order6[r] = 0xFFFFFFFFu;
    __syncthreads();
    for (unsigned c = tid; c < M; c += 256) {
        u64 key = sm.fb.lk[c];
        int rank = 0;
        for (unsigned j = 0; j < M; ++j) rank += (sm.fb.lk[j] < key) ? 1 : 0;
        if (rank < NPRE) order6[rank] = (unsigned)key;
    }
    __syncthreads();
    for (int r = tid; r < NPRE; r += 256) {
        unsigned idx = order6[r];
        float4 b = make_float4(0.f, 0.f, 0.f, 0.f);
        if (idx < (unsigned)n) b = decode_box(anchor[idx], loc[idx], ih, iw);
        roi6[r] = b;
    }
    __syncthreads();
    if (tid < 64) {
        int lane = tid;
        int nk2 = 0;
        for (int i = 0; i < NPRE; i++) {
            float4 b = roi6[i];
            float hs = b.z - b.x, wd = b.w - b.y;
            if (!(hs >= MINSZ && wd >= MINSZ)) continue;
            float ab = hs * wd;
            bool sup = false;
            for (int base = 0; base < nk2 && !sup; base += 64) {
                int t = base + lane;
                bool s = false;
                if (t < nk2) {
                    float yy1 = fmaxf(b.x, sm.fb.y1[t]);
                    float xx1 = fmaxf(b.y, sm.fb.x1[t]);
                    float yy2 = fminf(b.z, sm.fb.y2[t]);
                    float xx2 = fminf(b.w, sm.fb.x2[t]);
                    float inter = fmaxf(yy2 - yy1, 0.0f) * fmaxf(xx2 - xx1, 0.0f);
                    float iou = inter / (sm.fb.ar[t] + ab - inter);
                    s = iou > NMS_T;
                }
                sup = (__ballot(s) != 0ULL);
            }
            if (!sup) {
                if (lane == 0) {
                    sm.fb.y1[nk2] = b.x; sm.fb.x1[nk2] = b.y;
                    sm.fb.y2[nk2] = b.z; sm.fb.x2[nk2] = b.w; sm.fb.ar[nk2] = ab;
                }
                nk2++;
                if (nk2 == NPOST) break;
            }
        }
        for (int k = lane; k < NPOST; k += 64) {
            float4 o = make_float4(0.f, 0.f, 0.f, 0.f);
            if (k < nk2) o = make_float4(sm.fb.y1[k], sm.fb.x1[k], sm.fb.y2[k], sm.fb.x2[k]);
            out4[k] = o;
        }
    }
}

extern "C" void kernel_launch(void* const* d_in, const int* in_sizes, int n_in,
                              void* d_out, int out_size, void* d_ws, size_t ws_size,
                              hipStream_t stream) {
    const float4* loc    = (const float4*)d_in[0];
    const float*  score  = (const float*)d_in[1];
    const float4* anchor = (const float4*)d_in[2];
    const int*    ph     = (const int*)d_in[3];
    const int*    pw     = (const int*)d_in[4];
    int n = in_sizes[1];

    char* ws = (char*)d_ws;
    u64*      cand6  = (u64*)(ws + OFF_CAND6);
    u64*      candA  = (u64*)(ws + OFF_CANDA);
    unsigned* order6 = (unsigned*)(ws + OFF_ORDER6);
    float4*   roi6   = (float4*)(ws + OFF_ROI6);
    u64*      gmatT  = (u64*)(ws + OFF_GMAT);
    unsigned* slots  = (unsigned*)(ws + OFF_SLOT);
    unsigned* cnts   = (unsigned*)(ws + OFF_CNT);
    float* out = (float*)d_out;

    k_hist    <<<dim3(NSLOT), dim3(256), 0, stream>>>(score, n, slots, cnts);
    k_collect <<<dim3(GRIDC), dim3(256), 0, stream>>>(loc, score, anchor, ph, pw, n, slots,
                                                      candA, cnts);
    k_rankmat <<<dim3(GRIDR), dim3(256), 0, stream>>>(loc, score, anchor, ph, pw, n,
                                                      candA, cand6, cnts, gmatT,
                                                      order6, roi6, out);
}